// Round 7
// baseline (349.234 us; speedup 1.0000x reference)
//
#include <hip/hip_runtime.h>
#include <math.h>

#define NCAP 10
#define IC   6912
#define NJG  384                  // j-groups (18 j each)
#define NSLOT (NJG * 2)           // part slots (x2 b-halves)
#define WPAIRS ((IC * NCAP) / 2)  // 34560 W tile-pairs

typedef __attribute__((ext_vector_type(4))) float f32x4;
typedef __attribute__((ext_vector_type(8))) short bf16x8;

// fp32 -> bf16 RNE
static __device__ inline unsigned short f2bf(float f) {
    unsigned int u = __float_as_uint(f);
    unsigned int r = u + 0x7FFFu + ((u >> 16) & 1u);
    return (unsigned short)(r >> 16);
}

// Prep (R6-proven): blocks <1024 transpose W into MFMA A-fragment order;
// blocks >=1024 (one per j) convert x into B-fragment-order bf16.
__global__ __launch_bounds__(256) void prep_kernel(
    const float* __restrict__ x, const float* __restrict__ W,
    unsigned short* __restrict__ w_t, unsigned short* __restrict__ x_t)
{
    __shared__ float lds[4 * 1312];
    const int tid  = threadIdx.x;
    const int lane = tid & 63;
    const int wv   = tid >> 6;

    if (blockIdx.x < 1024) {
        float* L0 = lds + wv * 1312;
        const int gw = blockIdx.x * 4 + wv;
        const int lr  = lane & 31;
        const int reg = lane >> 5;
        const int ia  = lr >> 2, oq = lr & 3;
        const int o   = lr & 15, kq2 = lr >> 4;
        const float4* W4 = (const float4*)W;
        int itc = 0;
        for (int p = gw; p < WPAIRS; p += 4096, ++itc) {
            float* L = L0 + (itc & 1) * 656;
            const int tl = p * 2 + reg;          // tile id = j*10 + n
            const int n = tl % 10, j = tl / 10;
            const float4* src = W4 + ((size_t)n * IC + j) * 64;
            float4 a = src[lr];
            float4 c = src[lr + 32];
            *(float4*)&L[reg * 328 + ia * 20 + oq * 4] = a;
            *(float4*)&L[reg * 328 + (ia + 8) * 20 + oq * 4] = c;
            bf16x8 fr;
            #pragma unroll
            for (int t = 0; t < 8; ++t)
                fr[t] = (short)f2bf(L[reg * 328 + (kq2 * 8 + t) * 20 + o]);
            *(bf16x8*)&w_t[(size_t)tl * 256 + lr * 8] = fr;
        }
    } else {
        const int j  = blockIdx.x - 1024;        // 0..6911
        const int bg = wv;                       // b-group of 16
        if (lane < 32) {
            const int bl = lane & 15, kq = lane >> 4;
            const float* xp = x + ((size_t)(bg * 16 + bl) * IC + j) * 16 + kq * 8;
            float4 x0 = *(const float4*)xp;
            float4 x1 = *(const float4*)(xp + 4);
            bf16x8 fr;
            fr[0] = (short)f2bf(x0.x); fr[1] = (short)f2bf(x0.y);
            fr[2] = (short)f2bf(x0.z); fr[3] = (short)f2bf(x0.w);
            fr[4] = (short)f2bf(x1.x); fr[5] = (short)f2bf(x1.y);
            fr[6] = (short)f2bf(x1.z); fr[7] = (short)f2bf(x1.w);
            *(bf16x8*)&x_t[((size_t)j * 4 + bg) * 256 + lane * 8] = fr;
        }
    }
}

// Routing sweep = R5 structure (best measured) with the spill fix:
// __launch_bounds__(256,2) raises the VGPR cap to 256 so sac[10]+vv[10]+u[10]
// live in registers with NO scratch spills (R6's WRITE_SIZE=106MB was spill
// traffic at the 84-VGPR cap). x comes from coalesced bf16 x_t fragments.
// Block 256 = 4 waves = bg_l(2) x jw(2); covers 32 b's (bh half), 18 j's.
// Layouts (R2/R5/R6-proven): A[m=o=lane&15][k=(lane>>4)*8+t], B[k][b=lane&15],
// D col=lane&15(=b) row=(lane>>4)*4+reg(=o); K 16->32 zero-padded via zero
// fragments on lanes>=32.
__global__ __launch_bounds__(256, 2) void sweep_kernel(
    const unsigned short* __restrict__ x_t, const unsigned short* __restrict__ w_t,
    const float* __restrict__ vsum, float* __restrict__ part, int iter)
{
    __shared__ float cbuf[32 * 164];         // jw-combine buffer (padded)

    const int tid  = threadIdx.x;
    const int lane = tid & 63;
    const int wave = tid >> 6;
    const int bl   = lane & 15;
    const int kq   = lane >> 4;
    const bool act = (lane < 32);
    const int bh   = blockIdx.x & 1;
    const int jg   = blockIdx.x >> 1;
    const int bg_l = wave & 1;
    const int jw   = wave >> 1;
    const int b    = bh * 32 + bg_l * 16 + bl;
    const int j0   = jg * 18 + jw * 9;
    const int bgg  = bh * 2 + bg_l;          // global b-group 0..3

    const f32x4 zf = (f32x4){0.f, 0.f, 0.f, 0.f};
    const bf16x8 zb = (bf16x8){0, 0, 0, 0, 0, 0, 0, 0};

    f32x4 vv[NCAP];
    if (iter > 0) {
        #pragma unroll
        for (int n = 0; n < NCAP; ++n)
            vv[n] = *(const f32x4*)&vsum[(b * NCAP + n) * 16 + kq * 4];
    }

    f32x4 sac[NCAP];
    #pragma unroll
    for (int n = 0; n < NCAP; ++n) sac[n] = zf;

    for (int jt = 0; jt < 9; ++jt) {
        const int j = j0 + jt;

        bf16x8 xb = zb;
        if (act)
            xb = *(const bf16x8*)&x_t[((size_t)j * 4 + bgg) * 256 + lane * 8];

        f32x4 u[NCAP];
        #pragma unroll
        for (int n = 0; n < NCAP; ++n) {
            bf16x8 af = zb;
            if (act)
                af = *(const bf16x8*)&w_t[((size_t)j * NCAP + n) * 256 + lane * 8];
            u[n] = __builtin_amdgcn_mfma_f32_16x16x32_bf16(af, xb, zf, 0, 0, 0);
        }

        if (iter == 0) {
            #pragma unroll
            for (int n = 0; n < NCAP; ++n) {
                sac[n][0] = fmaf(0.1f, u[n][0], sac[n][0]);
                sac[n][1] = fmaf(0.1f, u[n][1], sac[n][1]);
                sac[n][2] = fmaf(0.1f, u[n][2], sac[n][2]);
                sac[n][3] = fmaf(0.1f, u[n][3], sac[n][3]);
            }
        } else {
            float bb_[NCAP];
            #pragma unroll
            for (int n = 0; n < NCAP; ++n) {
                float p = u[n][0] * vv[n][0] + u[n][1] * vv[n][1]
                        + u[n][2] * vv[n][2] + u[n][3] * vv[n][3];
                p += __shfl_xor(p, 16);      // reduce the 4 o-quads
                p += __shfl_xor(p, 32);
                bb_[n] = p;
            }
            // softmax over n (no max-sub; |bb| small, fp32 exp safe — R5-proven)
            float ssum = 0.f;
            float c[NCAP];
            #pragma unroll
            for (int n = 0; n < NCAP; ++n) { c[n] = __expf(bb_[n]); ssum += c[n]; }
            const float inv = 1.0f / ssum;
            #pragma unroll
            for (int n = 0; n < NCAP; ++n) {
                const float cn = c[n] * inv;
                sac[n][0] = fmaf(cn, u[n][0], sac[n][0]);
                sac[n][1] = fmaf(cn, u[n][1], sac[n][1]);
                sac[n][2] = fmaf(cn, u[n][2], sac[n][2]);
                sac[n][3] = fmaf(cn, u[n][3], sac[n][3]);
            }
        }
    }

    // combine jw=1 into jw=0 (one barrier per block, at the very end)
    const int sb = (bg_l * 16 + bl) * 164 + kq * 4;
    if (jw == 1) {
        #pragma unroll
        for (int n = 0; n < NCAP; ++n)
            *(f32x4*)&cbuf[sb + n * 16] = sac[n];
    }
    __syncthreads();
    if (jw == 0) {
        float* pp = part + (size_t)blockIdx.x * 5120;
        #pragma unroll
        for (int n = 0; n < NCAP; ++n) {
            f32x4 t = *(const f32x4*)&cbuf[sb + n * 16];
            t[0] += sac[n][0]; t[1] += sac[n][1];
            t[2] += sac[n][2]; t[3] += sac[n][3];
            *(f32x4*)&pp[(bg_l * 16 + bl) * 160 + n * 16 + kq * 4] = t;
        }
    }
}

// Fused reduce (NSLOT slots -> s) + squash + vsum/out. Grid 160 x 256.
__global__ __launch_bounds__(256) void reduce_kernel(
    const float* __restrict__ part, float* __restrict__ vsum,
    float* __restrict__ out, int iter)
{
    __shared__ float lds[3 * 64];
    const int tid = threadIdx.x;
    const int gi = tid & 63, rq = tid >> 6;
    const int g  = blockIdx.x * 64 + gi;          // 0..10239
    const int bh = (g >= 5120) ? 1 : 0;
    const float* p0 = part + bh * 5120 + (g - bh * 5120);
    float acc = 0.f;
    for (int k = rq * 96; k < rq * 96 + 96; ++k)
        acc += p0[(size_t)k * 10240];
    if (rq > 0) lds[(rq - 1) * 64 + gi] = acc;
    __syncthreads();
    if (rq == 0) {
        acc += lds[gi] + lds[64 + gi] + lds[128 + gi];
        float sq = acc * acc;                     // squash over o = bits 0..3
        sq += __shfl_xor(sq, 1);
        sq += __shfl_xor(sq, 2);
        sq += __shfl_xor(sq, 4);
        sq += __shfl_xor(sq, 8);
        float scale = (sq / (1.f + sq)) / sqrtf(sq + 1e-7f);
        float v = scale * acc;
        if (iter == 2)      out[g] = v;
        else if (iter == 0) vsum[g] = v;
        else                vsum[g] += v;
    }
}

extern "C" void kernel_launch(void* const* d_in, const int* in_sizes, int n_in,
                              void* d_out, int out_size, void* d_ws, size_t ws_size,
                              hipStream_t stream) {
    (void)in_sizes; (void)n_in; (void)out_size; (void)ws_size;
    const float* x = (const float*)d_in[0];   // [64, 6912, 16]
    const float* W = (const float*)d_in[1];   // [10, 6912, 16, 16]
    float* out = (float*)d_out;               // [64, 10, 16]

    const size_t wt_sh = (size_t)IC * NCAP * 256;   // shorts (35.4 MB)
    const size_t xt_sh = (size_t)IC * 4 * 256;      // shorts (14.2 MB)
    const size_t part_f = (size_t)NSLOT * 5120;     // floats (15.7 MB)

    unsigned short* w_t = (unsigned short*)d_ws;
    unsigned short* x_t = w_t + wt_sh;
    float* part = (float*)(x_t + xt_sh);
    float* vsum = part + part_f;

    prep_kernel<<<1024 + IC, 256, 0, stream>>>(x, W, w_t, x_t);
    for (int iter = 0; iter < 3; ++iter) {
        sweep_kernel<<<NSLOT, 256, 0, stream>>>(x_t, w_t, vsum, part, iter);
        reduce_kernel<<<160, 256, 0, stream>>>(part, vsum, out, iter);
    }
}